// Round 4
// baseline (153.267 us; speedup 1.0000x reference)
//
#include <hip/hip_runtime.h>
#include <hip/hip_bf16.h>
#include <math.h>

#define NROWS 4096
#define DDIM  512
#define BM    128
#define BK    64
#define NT    (DDIM / BK)              // 8 K-steps
#define NBLK  (NROWS / BM)             // 32
#define NTRI  (NBLK * (NBLK + 1) / 2)  // 528 upper-triangle blocks

static constexpr float ALPHA = 10.0f;
static constexpr float BETA  = 2.0f;
static constexpr float BASE  = 0.5f;

typedef short bf16x8 __attribute__((ext_vector_type(8)));
typedef float f32x4 __attribute__((ext_vector_type(4)));

// ---- sortable-uint encoding for float atomic min/max ----
__device__ __forceinline__ unsigned enc_f32(float f) {
  unsigned b = __float_as_uint(f);
  return (b & 0x80000000u) ? ~b : (b | 0x80000000u);
}
__device__ __forceinline__ float dec_f32(unsigned u) {
  unsigned b = (u & 0x80000000u) ? (u & 0x7fffffffu) : ~u;
  return __uint_as_float(b);
}
__device__ __forceinline__ unsigned f2bf(float f) {
  __hip_bfloat16 h = __float2bfloat16(f);  // RNE
  return (unsigned)*reinterpret_cast<unsigned short*>(&h);
}
__device__ __forceinline__ float bf2f(unsigned short u) {
  return __uint_as_float(((unsigned)u) << 16);
}

#define GLOAD_LDS16(g, l)                                              \
  __builtin_amdgcn_global_load_lds(                                    \
      (const __attribute__((address_space(1))) void*)(g),              \
      (__attribute__((address_space(3))) void*)(l), 16, 0, 0)

// ---- convert X f32 -> bf16 (packed), f32 self-dot, init all accumulators ----
__global__ __launch_bounds__(256) void convert_init_k(
    const float* __restrict__ X, unsigned short* __restrict__ Xb,
    float* __restrict__ selfsim, unsigned* __restrict__ minb,
    unsigned* __restrict__ maxb, float* __restrict__ ps,
    float* __restrict__ ns, float* __restrict__ lacc) {
  const int gid = blockIdx.x * 256 + threadIdx.x;
  if (gid < NROWS) {
    minb[gid] = 0xFF800000u;  // enc(+inf)
    maxb[gid] = 0x007FFFFFu;  // enc(-inf)
    ps[gid] = 0.0f;
    ns[gid] = 0.0f;
  }
  if (gid < 8) lacc[gid] = 0.0f;

  const int wid = threadIdx.x >> 6, lane = threadIdx.x & 63;
  const int r = blockIdx.x * 4 + wid;
  const size_t base = (size_t)r * DDIM + lane * 8;
  const float4 v0 = *reinterpret_cast<const float4*>(X + base);
  const float4 v1 = *reinterpret_cast<const float4*>(X + base + 4);
  uint4 u;
  u.x = f2bf(v0.x) | (f2bf(v0.y) << 16);
  u.y = f2bf(v0.z) | (f2bf(v0.w) << 16);
  u.z = f2bf(v1.x) | (f2bf(v1.y) << 16);
  u.w = f2bf(v1.z) | (f2bf(v1.w) << 16);
  *reinterpret_cast<uint4*>(Xb + base) = u;

  float sd = v0.x * v0.x;
  sd = fmaf(v0.y, v0.y, sd); sd = fmaf(v0.z, v0.z, sd); sd = fmaf(v0.w, v0.w, sd);
  sd = fmaf(v1.x, v1.x, sd); sd = fmaf(v1.y, v1.y, sd);
  sd = fmaf(v1.z, v1.z, sd); sd = fmaf(v1.w, v1.w, sd);
  #pragma unroll
  for (int off = 1; off < 64; off <<= 1) sd += __shfl_xor(sd, off);
  if (lane == 0) selfsim[r] = sd;
}

// stage one 128x64 bf16 tile (16 KB): pre-swizzled global src, linear LDS dst
#define STAGE1(dst, rowbase, t)                                                \
  do {                                                                         \
    const int kb_ = (t) * (BK * 2);                                            \
    _Pragma("unroll")                                                          \
    for (int c_ = 0; c_ < 4; ++c_) {                                           \
      const int lin_ = (c_ * 256 + tid) * 16;                                  \
      const int row_ = lin_ >> 7;                                              \
      const int col_ = lin_ & 127;                                             \
      const int scol_ = col_ ^ ((row_ & 7) << 4);                              \
      GLOAD_LDS16(Xbb + (size_t)((rowbase) + row_) * (DDIM * 2) + kb_ + scol_, \
                  (char*)(dst) + lin_);                                        \
    }                                                                          \
  } while (0)

// PASS 0: min/max epilogue. PASS 1: exp-sum + last-row-stats epilogue.
template <int PASS>
__global__ __launch_bounds__(256) void gemm_pass(
    const unsigned short* __restrict__ Xb, const int* __restrict__ tgt,
    const float* __restrict__ selfsim,
    unsigned* __restrict__ minb, unsigned* __restrict__ maxb,
    float* __restrict__ ps, float* __restrict__ ns,
    float* __restrict__ lacc, const float* __restrict__ marginp) {
  __shared__ unsigned short lds[2][2][BM * BK] __attribute__((aligned(16)));

  int kk0 = blockIdx.x, bi = 0;
  while (kk0 >= NBLK - bi) { kk0 -= NBLK - bi; ++bi; }
  const int bj = bi + kk0;
  const int i0 = bi * BM, j0 = bj * BM;
  const bool diagb = (bi == bj);

  const int tid = threadIdx.x;
  const int w = tid >> 6, lane = tid & 63;
  const int wr = w >> 1, wc = w & 1;
  const int g = lane >> 4, q = lane & 15;
  const char* Xbb = (const char*)Xb;

  f32x4 acc[4][4];
  #pragma unroll
  for (int m = 0; m < 4; ++m)
    #pragma unroll
    for (int n = 0; n < 4; ++n) acc[m][n] = (f32x4)0.0f;

  STAGE1(&lds[0][0][0], i0, 0);
  if (!diagb) STAGE1(&lds[0][1][0], j0, 0);
  __syncthreads();
  int cur = 0;
  for (int t = 0; t < NT; ++t) {
    if (t + 1 < NT) {
      STAGE1(&lds[cur ^ 1][0][0], i0, t + 1);
      if (!diagb) STAGE1(&lds[cur ^ 1][1][0], j0, t + 1);
    }
    const char* Ab = (const char*)&lds[cur][0][0];
    const char* Bb = diagb ? Ab : (const char*)&lds[cur][1][0];
    #pragma unroll
    for (int kk = 0; kk < 2; ++kk) {
      bf16x8 a[4], b[4];
      #pragma unroll
      for (int fm = 0; fm < 4; ++fm) {
        const int row = wr * 64 + fm * 16 + q;
        const int col = (kk * 64 + g * 16) ^ ((row & 7) << 4);
        a[fm] = *reinterpret_cast<const bf16x8*>(Ab + row * 128 + col);
      }
      #pragma unroll
      for (int fn = 0; fn < 4; ++fn) {
        const int row = wc * 64 + fn * 16 + q;
        const int col = (kk * 64 + g * 16) ^ ((row & 7) << 4);
        b[fn] = *reinterpret_cast<const bf16x8*>(Bb + row * 128 + col);
      }
      #pragma unroll
      for (int fm = 0; fm < 4; ++fm)
        #pragma unroll
        for (int fn = 0; fn < 4; ++fn)
          acc[fm][fn] = __builtin_amdgcn_mfma_f32_16x16x32_bf16(a[fm], b[fn], acc[fm][fn], 0, 0, 0);
    }
    __syncthreads();
    cur ^= 1;
  }

  // ---- epilogue ----
  const int rbase = i0 + wr * 64;
  int cg[4], tj[4];
  #pragma unroll
  for (int fn = 0; fn < 4; ++fn) {
    cg[fn] = j0 + wc * 64 + fn * 16 + q;
    tj[fn] = tgt[cg[fn]];
  }
  int ti[16];
  #pragma unroll
  for (int fm = 0; fm < 4; ++fm)
    #pragma unroll
    for (int reg = 0; reg < 4; ++reg)
      ti[fm * 4 + reg] = tgt[rbase + fm * 16 + g * 4 + reg];

  if constexpr (PASS == 0) {
    // row-side min(pos)/max(neg)
    #pragma unroll
    for (int fm = 0; fm < 4; ++fm) {
      #pragma unroll
      for (int reg = 0; reg < 4; ++reg) {
        const int r = rbase + fm * 16 + g * 4 + reg;
        const int tr = ti[fm * 4 + reg];
        float mnp = INFINITY, mxn = -INFINITY;
        #pragma unroll
        for (int fn = 0; fn < 4; ++fn) {
          float s = acc[fm][fn][reg];
          if (diagb && r == cg[fn]) s = selfsim[r];  // f32 diag override
          if (tj[fn] == tr) {
            if (s < 1.0f) mnp = fminf(mnp, s);
          } else {
            mxn = fmaxf(mxn, s);
          }
        }
        #pragma unroll
        for (int off = 1; off < 16; off <<= 1) {
          mnp = fminf(mnp, __shfl_xor(mnp, off));
          mxn = fmaxf(mxn, __shfl_xor(mxn, off));
        }
        if (q == 0) {
          if (mnp != INFINITY) atomicMin(minb + r, enc_f32(mnp));
          if (mxn != -INFINITY) atomicMax(maxb + r, enc_f32(mxn));
        }
      }
    }
    if (!diagb) {  // col-side
      #pragma unroll
      for (int fn = 0; fn < 4; ++fn) {
        const int tc = tj[fn];
        float mnp = INFINITY, mxn = -INFINITY;
        #pragma unroll
        for (int fm = 0; fm < 4; ++fm)
          #pragma unroll
          for (int reg = 0; reg < 4; ++reg) {
            const float s = acc[fm][fn][reg];
            if (ti[fm * 4 + reg] == tc) {
              if (s < 1.0f) mnp = fminf(mnp, s);
            } else {
              mxn = fmaxf(mxn, s);
            }
          }
        mnp = fminf(mnp, __shfl_xor(mnp, 16));
        mnp = fminf(mnp, __shfl_xor(mnp, 32));
        mxn = fmaxf(mxn, __shfl_xor(mxn, 16));
        mxn = fmaxf(mxn, __shfl_xor(mxn, 32));
        if (lane < 16) {
          if (mnp != INFINITY) atomicMin(minb + cg[fn], enc_f32(mnp));
          if (mxn != -INFINITY) atomicMax(maxb + cg[fn], enc_f32(mxn));
        }
      }
    }
  } else {
    const float margin = *marginp;
    float mpr[16], mxr[16];
    #pragma unroll
    for (int fm = 0; fm < 4; ++fm)
      #pragma unroll
      for (int reg = 0; reg < 4; ++reg) {
        const int r = rbase + fm * 16 + g * 4 + reg;
        mpr[fm * 4 + reg] = dec_f32(minb[r]);
        mxr[fm * 4 + reg] = dec_f32(maxb[r]);
      }
    float mpc[4], mxc[4], cps[4], cns[4];
    #pragma unroll
    for (int fn = 0; fn < 4; ++fn) {
      mpc[fn] = dec_f32(minb[cg[fn]]);
      mxc[fn] = dec_f32(maxb[cg[fn]]);
      cps[fn] = 0.0f; cns[fn] = 0.0f;
    }
    float wlsp = 0, wlcp = 0, wlsn = 0, wlcn = 0;  // last ROW stats (row-side)
    float clsp = 0, clcp = 0, clsn = 0, clcn = 0;  // last row via col-side

    #pragma unroll
    for (int fm = 0; fm < 4; ++fm) {
      #pragma unroll
      for (int reg = 0; reg < 4; ++reg) {
        const int idx = fm * 4 + reg;
        const int r = rbase + fm * 16 + g * 4 + reg;
        const int tr = ti[idx];
        const bool lastrow = (r == NROWS - 1);
        float rps = 0.0f, rns = 0.0f;
        #pragma unroll
        for (int fn = 0; fn < 4; ++fn) {
          float s = acc[fm][fn][reg];
          if (diagb && r == cg[fn])
            s = bf2f((unsigned short)f2bf(selfsim[r]));  // rounds to 1.0 -> excluded
          const bool collast = (!diagb) && (cg[fn] == NROWS - 1);
          if (tj[fn] != tr) {
            const float en = __expf(ALPHA * (s - BASE));
            if (s + margin - mpr[idx] > 0.0f) rns += en;
            if (!diagb && s + margin - mpc[fn] > 0.0f) cns[fn] += en;
            if (lastrow) { wlsn += s; wlcn += 1.0f; }
            if (collast) { clsn += s; clcn += 1.0f; }
          } else if (s < 1.0f) {
            const float ep = __expf(-BETA * (s - BASE));
            if (mxr[idx] - s + margin > 0.0f) rps += ep;
            if (!diagb && mxc[fn] - s + margin > 0.0f) cps[fn] += ep;
            if (lastrow) { wlsp += s; wlcp += 1.0f; }
            if (collast) { clsp += s; clcp += 1.0f; }
          }
        }
        #pragma unroll
        for (int off = 1; off < 16; off <<= 1) {
          rps += __shfl_xor(rps, off);
          rns += __shfl_xor(rns, off);
        }
        if (q == 0) {
          if (rps != 0.0f) atomicAdd(ps + r, rps);
          if (rns != 0.0f) atomicAdd(ns + r, rns);
        }
      }
    }
    // row-side last-row stats: rows 4032..4095 live in wave wr==1 of bi==31 (diag block)
    if (bi == NBLK - 1 && wr == 1 && diagb) {
      #pragma unroll
      for (int off = 1; off < 16; off <<= 1) {
        wlsp += __shfl_xor(wlsp, off); wlcp += __shfl_xor(wlcp, off);
        wlsn += __shfl_xor(wlsn, off); wlcn += __shfl_xor(wlcn, off);
      }
      if (lane == 48) {  // g==3, q==0: holds the r==4095 group's sum
        if (wlcp != 0.0f) { atomicAdd(lacc + 0, wlsp); atomicAdd(lacc + 1, wlcp); }
        if (wlcn != 0.0f) { atomicAdd(lacc + 2, wlsn); atomicAdd(lacc + 3, wlcn); }
      }
    }
    if (!diagb) {
      #pragma unroll
      for (int fn = 0; fn < 4; ++fn) {
        float v1 = cps[fn], v2 = cns[fn];
        v1 += __shfl_xor(v1, 16); v1 += __shfl_xor(v1, 32);
        v2 += __shfl_xor(v2, 16); v2 += __shfl_xor(v2, 32);
        if (lane < 16) {
          if (v1 != 0.0f) atomicAdd(ps + cg[fn], v1);
          if (v2 != 0.0f) atomicAdd(ns + cg[fn], v2);
        }
      }
      if (bj == NBLK - 1 && wc == 1) {  // col 4095 in this wave (fn==3, q==15 lanes)
        clsp += __shfl_xor(clsp, 16); clsp += __shfl_xor(clsp, 32);
        clcp += __shfl_xor(clcp, 16); clcp += __shfl_xor(clcp, 32);
        clsn += __shfl_xor(clsn, 16); clsn += __shfl_xor(clsn, 32);
        clcn += __shfl_xor(clcn, 16); clcn += __shfl_xor(clcn, 32);
        if (lane == 15) {
          if (clcp != 0.0f) { atomicAdd(lacc + 0, clsp); atomicAdd(lacc + 1, clcp); }
          if (clcn != 0.0f) { atomicAdd(lacc + 2, clsn); atomicAdd(lacc + 3, clcn); }
        }
      }
    }
  }
}

__device__ __forceinline__ float block_sum(float v) {
  __shared__ float sh[4];
  #pragma unroll
  for (int off = 32; off > 0; off >>= 1) v += __shfl_down(v, off);
  if ((threadIdx.x & 63) == 0) sh[threadIdx.x >> 6] = v;
  __syncthreads();
  float r = sh[0] + sh[1] + sh[2] + sh[3];
  __syncthreads();
  return r;
}

__global__ __launch_bounds__(256) void finalize_k(
    const float* __restrict__ ps, const float* __restrict__ ns,
    const float* __restrict__ lacc, float* __restrict__ out) {
  float lsum = 0.0f, inval = 0.0f;
  #pragma unroll
  for (int c = 0; c < 16; ++c) {
    const int i = c * 256 + threadIdx.x;
    const float p = ps[i], n = ns[i];
    if (p > 0.0f && n > 0.0f) {
      lsum += (2.0f / BETA) * log1pf(p) + (2.0f / ALPHA) * log1pf(n);
    } else {
      inval += 1.0f;
    }
  }
  lsum = block_sum(lsum);
  inval = block_sum(inval);
  if (threadIdx.x == 0) {
    out[0] = lsum / (float)NROWS;
    out[1] = inval / (float)NROWS;
    out[2] = lacc[0] / fmaxf(lacc[1], 1.0f);
    out[3] = lacc[2] / fmaxf(lacc[3], 1.0f);
  }
}

extern "C" void kernel_launch(void* const* d_in, const int* in_sizes, int n_in,
                              void* d_out, int out_size, void* d_ws, size_t ws_size,
                              hipStream_t stream) {
  const float* X = (const float*)d_in[0];
  const int* tgt = (const int*)d_in[1];
  const float* marginp = (const float*)d_in[2];
  float* out = (float*)d_out;

  char* ws = (char*)d_ws;
  unsigned* minb = (unsigned*)ws;                 // @0     16 KB
  unsigned* maxb = (unsigned*)(ws + (16 << 10));  // @16K   16 KB
  float* ps = (float*)(ws + (32 << 10));          // @32K   16 KB
  float* ns = (float*)(ws + (48 << 10));          // @48K   16 KB
  float* lacc = (float*)(ws + (64 << 10));        // @64K   small
  float* selfsim = (float*)(ws + (80 << 10));     // @80K   16 KB
  unsigned short* Xb = (unsigned short*)(ws + (128 << 10));  // 4 MB

  convert_init_k<<<dim3(NROWS / 4), 256, 0, stream>>>(X, Xb, selfsim, minb, maxb, ps, ns, lacc);
  gemm_pass<0><<<dim3(NTRI), 256, 0, stream>>>(Xb, tgt, selfsim, minb, maxb, ps, ns, lacc, marginp);
  gemm_pass<1><<<dim3(NTRI), 256, 0, stream>>>(Xb, tgt, selfsim, minb, maxb, ps, ns, lacc, marginp);
  finalize_k<<<dim3(1), 256, 0, stream>>>(ps, ns, lacc, out);
}